// Round 11
// baseline (68.116 us; speedup 1.0000x reference)
//
#include <hip/hip_runtime.h>
#include <hip/hip_bf16.h>

// GAT layer, N=4096, C_IN=C_OUT=256, HEADS=4, C_HEAD=64.
// Pipeline (2 kernels):
//  K1f: h = X@W^T + b in-register; writes hB (bf16 MFMA-B-fragment order)
//       + e_src/e_dst (x log2e). h fp32 never materialized.
//  K3: masked softmax (fixed m=0) + P@H reading RAW adj (no pre-packed
//      bitmask, no k0): per td, 16 coalesced i32x4 loads give each lane its
//      8 adj ints/tile; bit-pack -> 8-bit mask -> 16-entry LDS LUT -> AND on
//      packed bf16. 32 i-rows per wave, 8 j-splits merged via LDS.
// Workspace: ~2.2 MB.

#define NN 4096
#define LOG2E 1.4426950408889634f

typedef float f32x4 __attribute__((ext_vector_type(4)));
typedef int i32x4 __attribute__((ext_vector_type(4)));
typedef unsigned int u32x2 __attribute__((ext_vector_type(2)));
typedef unsigned int u32x4 __attribute__((ext_vector_type(4)));
typedef unsigned short u16x4 __attribute__((ext_vector_type(4)));
typedef unsigned short u16x8 __attribute__((ext_vector_type(8)));
typedef __bf16 bf16x8 __attribute__((ext_vector_type(8)));

__device__ __forceinline__ unsigned short f2bf_rne(float f) {
    unsigned int u = __builtin_bit_cast(unsigned int, f);
    u += 0x7fffu + ((u >> 16) & 1u);
    return (unsigned short)(u >> 16);
}

__device__ __forceinline__ bf16x8 ld_cvt8(const float* __restrict__ p) {
    f32x4 x = *(const f32x4*)p;
    f32x4 y = *(const f32x4*)(p + 4);
    u16x8 u;
    u[0] = f2bf_rne(x[0]); u[1] = f2bf_rne(x[1]); u[2] = f2bf_rne(x[2]); u[3] = f2bf_rne(x[3]);
    u[4] = f2bf_rne(y[0]); u[5] = f2bf_rne(y[1]); u[6] = f2bf_rne(y[2]); u[7] = f2bf_rne(y[3]);
    return __builtin_bit_cast(bf16x8, u);
}

// ---------------- K1f: fused GEMM + hB-swizzle + e_src/e_dst ----------------
// 256 blocks x 256 thr. Block = 16 rows; wave hh owns cols [64hh,64hh+64) = head hh.
__global__ __launch_bounds__(256) void k1_fused(const float* __restrict__ X,
                                                const float* __restrict__ W,
                                                const float* __restrict__ bias,
                                                const float* __restrict__ a,
                                                unsigned short* __restrict__ hB,
                                                float* __restrict__ esrc,
                                                float* __restrict__ edst) {
    const int lane = threadIdx.x & 63;
    const int hh   = threadIdx.x >> 6;      // head / column group
    const int row  = lane & 15;
    const int kg   = lane >> 4;
    const int rowbase = blockIdx.x * 16;

    f32x4 acc[4];
#pragma unroll
    for (int n = 0; n < 4; ++n) acc[n] = (f32x4)0.f;

#pragma unroll
    for (int kk = 0; kk < 8; ++kk) {
        const int kb = kk * 32 + kg * 8;
        bf16x8 a0 = ld_cvt8(X + (rowbase + row) * 256 + kb);
#pragma unroll
        for (int n = 0; n < 4; ++n) {
            bf16x8 bb = ld_cvt8(W + (hh * 64 + n * 16 + row) * 256 + kb);
            acc[n] = __builtin_amdgcn_mfma_f32_16x16x32_bf16(a0, bb, acc[n], 0, 0, 0);
        }
    }

    // epilogue: bias, hB store (fragment order), e_src/e_dst dots
    // value acc[n][r] = h[rowbase+4kg+r][hh*64 + n*16 + row]
    // -> hB lane' = (rb2*2 + (kg>>1))*16 + row, e = (kg&1)*4 + r
    const int t   = rowbase >> 5;
    const int lp  = (((rowbase >> 4) & 1) * 2 + (kg >> 1)) * 16 + row;
    const int eoff = (kg & 1) * 4;
    unsigned short* hbb = hB + (hh * 128 + t) * 2048 + lp * 8 + eoff;

    float eS0 = 0.f, eS1 = 0.f, eS2 = 0.f, eS3 = 0.f;
    float eT0 = 0.f, eT1 = 0.f, eT2 = 0.f, eT3 = 0.f;
#pragma unroll
    for (int n = 0; n < 4; ++n) {
        const int col = hh * 64 + n * 16 + row;
        const float bv = bias[col];
        f32x4 hv;
        hv[0] = acc[n][0] + bv; hv[1] = acc[n][1] + bv;
        hv[2] = acc[n][2] + bv; hv[3] = acc[n][3] + bv;
        u16x4 us;
        us[0] = f2bf_rne(hv[0]); us[1] = f2bf_rne(hv[1]);
        us[2] = f2bf_rne(hv[2]); us[3] = f2bf_rne(hv[3]);
        *(u16x4*)(hbb + n * 512) = us;
        const float as_ = a[hh * 128 + n * 16 + row];
        const float ad_ = a[hh * 128 + 64 + n * 16 + row];
        eS0 += hv[0] * as_; eS1 += hv[1] * as_; eS2 += hv[2] * as_; eS3 += hv[3] * as_;
        eT0 += hv[0] * ad_; eT1 += hv[1] * ad_; eT2 += hv[2] * ad_; eT3 += hv[3] * ad_;
    }
#pragma unroll
    for (int d = 1; d < 16; d <<= 1) {
        eS0 += __shfl_xor(eS0, d); eS1 += __shfl_xor(eS1, d);
        eS2 += __shfl_xor(eS2, d); eS3 += __shfl_xor(eS3, d);
        eT0 += __shfl_xor(eT0, d); eT1 += __shfl_xor(eT1, d);
        eT2 += __shfl_xor(eT2, d); eT3 += __shfl_xor(eT3, d);
    }
    if (row == 0) {
        const int rb = hh * NN + rowbase + kg * 4;
        esrc[rb + 0] = eS0 * LOG2E; esrc[rb + 1] = eS1 * LOG2E;
        esrc[rb + 2] = eS2 * LOG2E; esrc[rb + 3] = eS3 * LOG2E;
        edst[rb + 0] = eT0 * LOG2E; edst[rb + 1] = eT1 * LOG2E;
        edst[rb + 2] = eT2 * LOG2E; edst[rb + 3] = eT3 * LOG2E;
    }
}

// ---------------- K3: raw-adj masked softmax (m=0) + P@H ----------------
// grid 512: ib = bx>>2 (32 rows), hh = bx&3. 8 waves = 8 j-splits of 512 j.
// Each wave: 2 row-groups (i0+row, i0+16+row) x 16 tiles of 32 j.
// Lane (row,kg) covers j = q*512 + td*128 + ti*32 + kg*8 + [0,8).
#define K3_MKP(AF, ES, M8) {                                                      \
    f32x4 s0v = E0 + (f32x4)(ES);                                                 \
    f32x4 s1v = E1 + (f32x4)(ES);                                                 \
    s0v = __builtin_elementwise_max(s0v, s0v * 0.2f);                             \
    s1v = __builtin_elementwise_max(s1v, s1v * 0.2f);                             \
    bf16x8 afv;                                                                   \
    afv[0] = (__bf16)__builtin_exp2f(s0v[0]);                                     \
    afv[1] = (__bf16)__builtin_exp2f(s0v[1]);                                     \
    afv[2] = (__bf16)__builtin_exp2f(s0v[2]);                                     \
    afv[3] = (__bf16)__builtin_exp2f(s0v[3]);                                     \
    afv[4] = (__bf16)__builtin_exp2f(s1v[0]);                                     \
    afv[5] = (__bf16)__builtin_exp2f(s1v[1]);                                     \
    afv[6] = (__bf16)__builtin_exp2f(s1v[2]);                                     \
    afv[7] = (__bf16)__builtin_exp2f(s1v[3]);                                     \
    u32x4 aw = __builtin_bit_cast(u32x4, afv);                                    \
    const u32x2 mk0 = mlut[(M8) & 15u];                                           \
    const u32x2 mk1 = mlut[((M8) >> 4) & 15u];                                    \
    aw[0] &= mk0[0]; aw[1] &= mk0[1];                                             \
    aw[2] &= mk1[0]; aw[3] &= mk1[1];                                             \
    AF = __builtin_bit_cast(bf16x8, aw);                                          \
}

__global__ __launch_bounds__(512, 4) void k3_flash(const int* __restrict__ adj,
                                                   const unsigned short* __restrict__ hB,
                                                   const float* __restrict__ esrc,
                                                   const float* __restrict__ edst,
                                                   float* __restrict__ out) {
    __shared__ float lacc[8][16][64];
    __shared__ float lls[8][16];
    __shared__ u32x2 mlut[16];

    const int lane = threadIdx.x & 63;
    const int q  = threadIdx.x >> 6;  // j-split 0..7 (512 j each)
    const int hh = blockIdx.x & 3;    // head
    const int ib = blockIdx.x >> 2;   // 0..127
    const int i0 = ib * 32;
    const int row = lane & 15;
    const int kg  = lane >> 4;

    if (threadIdx.x < 16) {
        const unsigned n = threadIdx.x;
        u32x2 m;
        m[0] = ((n & 1u) ? 0xFFFFu : 0u) | ((n & 2u) ? 0xFFFF0000u : 0u);
        m[1] = ((n & 4u) ? 0xFFFFu : 0u) | ((n & 8u) ? 0xFFFF0000u : 0u);
        mlut[n] = m;
    }
    __syncthreads();

    const float es0 = esrc[hh * NN + i0 + row];
    const float es1 = esrc[hh * NN + i0 + 16 + row];
    const int* adj0 = adj + (i0 + row) * NN + q * 512 + kg * 8;
    const int* adj1 = adj0 + 16 * NN;
    const float* eD = edst + hh * NN + q * 512 + kg * 8;
    const unsigned short* hBp = hB + ((hh * 128 + q * 16) * 256 + lane) * 8;

    // ones B-fragment: column 0 only
    u16x8 ou;
    const unsigned short ov = (row == 0) ? (unsigned short)0x3F80 : (unsigned short)0;
#pragma unroll
    for (int e = 0; e < 8; ++e) ou[e] = ov;
    const bf16x8 bOnes = __builtin_bit_cast(bf16x8, ou);

    f32x4 aA0 = (f32x4)0.f, aA1 = (f32x4)0.f, aA2 = (f32x4)0.f,
          aA3 = (f32x4)0.f, aA4 = (f32x4)0.f;
    f32x4 aB0 = (f32x4)0.f, aB1 = (f32x4)0.f, aB2 = (f32x4)0.f,
          aB3 = (f32x4)0.f, aB4 = (f32x4)0.f;

    for (int td = 0; td < 4; ++td) {
        // ---- load this td's adj ints (16 independent 16B loads), bit-pack ----
        unsigned w0 = 0, w1 = 0;
#pragma unroll
        for (int ti = 0; ti < 4; ++ti) {
            const i32x4 pa0 = *(const i32x4*)(adj0 + td * 128 + ti * 32);
            const i32x4 pa1 = *(const i32x4*)(adj0 + td * 128 + ti * 32 + 4);
            const i32x4 pb0 = *(const i32x4*)(adj1 + td * 128 + ti * 32);
            const i32x4 pb1 = *(const i32x4*)(adj1 + td * 128 + ti * 32 + 4);
            unsigned b0 = 0, b1 = 0;
#pragma unroll
            for (int e = 0; e < 4; ++e) {
                b0 |= (unsigned)(pa0[e] & 1) << e;
                b0 |= (unsigned)(pa1[e] & 1) << (4 + e);
                b1 |= (unsigned)(pb0[e] & 1) << e;
                b1 |= (unsigned)(pb1[e] & 1) << (4 + e);
            }
            w0 |= b0 << (ti * 8);
            w1 |= b1 << (ti * 8);
        }

        const float* eDt = eD + td * 128;
        const unsigned short* hBt = hBp + td * 8192;
#pragma unroll
        for (int ti = 0; ti < 4; ++ti) {
            const f32x4 E0 = *(const f32x4*)(eDt + ti * 32);
            const f32x4 E1 = *(const f32x4*)(eDt + ti * 32 + 4);
            const u16x8 B0 = *(const u16x8*)(hBt + ti * 2048);
            const u16x8 B1 = *(const u16x8*)(hBt + ti * 2048 + 512);
            const u16x8 B2 = *(const u16x8*)(hBt + ti * 2048 + 1024);
            const u16x8 B3 = *(const u16x8*)(hBt + ti * 2048 + 1536);
            bf16x8 af0, af1;
            K3_MKP(af0, es0, (w0 >> (ti * 8)))
            K3_MKP(af1, es1, (w1 >> (ti * 8)))
            aA0 = __builtin_amdgcn_mfma_f32_16x16x32_bf16(af0, __builtin_bit_cast(bf16x8, B0), aA0, 0, 0, 0);
            aA1 = __builtin_amdgcn_mfma_f32_16x16x32_bf16(af0, __builtin_bit_cast(bf16x8, B1), aA1, 0, 0, 0);
            aA2 = __builtin_amdgcn_mfma_f32_16x16x32_bf16(af0, __builtin_bit_cast(bf16x8, B2), aA2, 0, 0, 0);
            aA3 = __builtin_amdgcn_mfma_f32_16x16x32_bf16(af0, __builtin_bit_cast(bf16x8, B3), aA3, 0, 0, 0);
            aA4 = __builtin_amdgcn_mfma_f32_16x16x32_bf16(af0, bOnes, aA4, 0, 0, 0);
            aB0 = __builtin_amdgcn_mfma_f32_16x16x32_bf16(af1, __builtin_bit_cast(bf16x8, B0), aB0, 0, 0, 0);
            aB1 = __builtin_amdgcn_mfma_f32_16x16x32_bf16(af1, __builtin_bit_cast(bf16x8, B1), aB1, 0, 0, 0);
            aB2 = __builtin_amdgcn_mfma_f32_16x16x32_bf16(af1, __builtin_bit_cast(bf16x8, B2), aB2, 0, 0, 0);
            aB3 = __builtin_amdgcn_mfma_f32_16x16x32_bf16(af1, __builtin_bit_cast(bf16x8, B3), aB3, 0, 0, 0);
            aB4 = __builtin_amdgcn_mfma_f32_16x16x32_bf16(af1, bOnes, aB4, 0, 0, 0);
        }
    }

    // ---- merge pass 1: row-group 0 (rows i0 .. i0+15) ----
#pragma unroll
    for (int n = 0; n < 4; ++n) {
        f32x4 an = (n == 0) ? aA0 : (n == 1) ? aA1 : (n == 2) ? aA2 : aA3;
#pragma unroll
        for (int r = 0; r < 4; ++r)
            lacc[q][kg * 4 + r][n * 16 + row] = an[r];
    }
    if (row == 0) {
#pragma unroll
        for (int r = 0; r < 4; ++r) lls[q][kg * 4 + r] = aA4[r];
    }
    __syncthreads();
    if (threadIdx.x < 256) {
        const int idx = threadIdx.x * 4;
        const int r2 = idx >> 6;
        const int c  = idx & 63;
        f32x4 v = (f32x4)0.f;
        float l = 0.f;
#pragma unroll
        for (int q2 = 0; q2 < 8; ++q2) {
            v += *(const f32x4*)&lacc[q2][r2][c];
            l += lls[q2][r2];
        }
        const float inv = 1.f / l;
        f32x4 o;
        o[0] = v[0] * inv; o[1] = v[1] * inv; o[2] = v[2] * inv; o[3] = v[3] * inv;
        *(f32x4*)(out + (i0 + r2) * 256 + hh * 64 + c) = o;
    }
    __syncthreads();

    // ---- merge pass 2: row-group 1 (rows i0+16 .. i0+31) ----
#pragma unroll
    for (int n = 0; n < 4; ++n) {
        f32x4 an = (n == 0) ? aB0 : (n == 1) ? aB1 : (n == 2) ? aB2 : aB3;
#pragma unroll
        for (int r = 0; r < 4; ++r)
            lacc[q][kg * 4 + r][n * 16 + row] = an[r];
    }
    if (row == 0) {
#pragma unroll
        for (int r = 0; r < 4; ++r) lls[q][kg * 4 + r] = aB4[r];
    }
    __syncthreads();
    if (threadIdx.x < 256) {
        const int idx = threadIdx.x * 4;
        const int r2 = idx >> 6;
        const int c  = idx & 63;
        f32x4 v = (f32x4)0.f;
        float l = 0.f;
#pragma unroll
        for (int q2 = 0; q2 < 8; ++q2) {
            v += *(const f32x4*)&lacc[q2][r2][c];
            l += lls[q2][r2];
        }
        const float inv = 1.f / l;
        f32x4 o;
        o[0] = v[0] * inv; o[1] = v[1] * inv; o[2] = v[2] * inv; o[3] = v[3] * inv;
        *(f32x4*)(out + (i0 + 16 + r2) * 256 + hh * 64 + c) = o;
    }
}

extern "C" void kernel_launch(void* const* d_in, const int* in_sizes, int n_in,
                              void* d_out, int out_size, void* d_ws, size_t ws_size,
                              hipStream_t stream) {
    const float* X    = (const float*)d_in[0];
    const int*   adj  = (const int*)d_in[1];
    const float* W    = (const float*)d_in[2];
    const float* bias = (const float*)d_in[3];
    const float* a    = (const float*)d_in[4];
    float* out = (float*)d_out;

    char* ws = (char*)d_ws;
    unsigned short* hB   = (unsigned short*)(ws);                         // 2 MB
    float*          esrc = (float*)(ws + (2 << 20));                      // 64 KB (HEADS*N)
    float*          edst = (float*)(ws + (2 << 20) + (64 << 10));         // 64 KB (HEADS*N)

    k1_fused<<<256, 256, 0, stream>>>(X, W, bias, a, hB, esrc, edst);
    k3_flash<<<512, 512, 0, stream>>>(adj, hB, esrc, edst, out);
}

// Round 12
// 66.345 us; speedup vs baseline: 1.0267x; 1.0267x over previous
//
#include <hip/hip_runtime.h>
#include <hip/hip_bf16.h>

// GAT layer, N=4096, C_IN=C_OUT=256, HEADS=4, C_HEAD=64.
// Pipeline (2 kernels):
//  K1f: h = X@W^T + b in-register; writes hB (bf16 MFMA-B-fragment order)
//       + e_src/e_dst (x log2e). h fp32 never materialized.
//  K3: masked softmax (fixed m=0) + P@H. adj is staged global->LDS with
//      __builtin_amdgcn_global_load_lds (async DMA, no VGPR round-trip),
//      3-buffer 2-deep counted-vmcnt pipeline, XOR-swizzled LDS layout.
//      Grid 256 = hh*64+ib so the 4 head-blocks of each ib share an XCD's
//      L2 -> adj crosses HBM once. Block = 64 rows x 1 head slice... full:
//      block covers rows i0..i0+63 for head hh; 8 waves = 4 rowgroups x 2
//      j-halves; B-frag tiles shared across the 4 rg-waves via L1.
// Workspace: ~2.2 MB.

#define NN 4096
#define LOG2E 1.4426950408889634f

typedef float f32x4 __attribute__((ext_vector_type(4)));
typedef int i32x4 __attribute__((ext_vector_type(4)));
typedef unsigned int u32x2 __attribute__((ext_vector_type(2)));
typedef unsigned int u32x4 __attribute__((ext_vector_type(4)));
typedef unsigned short u16x4 __attribute__((ext_vector_type(4)));
typedef unsigned short u16x8 __attribute__((ext_vector_type(8)));
typedef __bf16 bf16x8 __attribute__((ext_vector_type(8)));

__device__ __forceinline__ unsigned short f2bf_rne(float f) {
    unsigned int u = __builtin_bit_cast(unsigned int, f);
    u += 0x7fffu + ((u >> 16) & 1u);
    return (unsigned short)(u >> 16);
}

__device__ __forceinline__ bf16x8 ld_cvt8(const float* __restrict__ p) {
    f32x4 x = *(const f32x4*)p;
    f32x4 y = *(const f32x4*)(p + 4);
    u16x8 u;
    u[0] = f2bf_rne(x[0]); u[1] = f2bf_rne(x[1]); u[2] = f2bf_rne(x[2]); u[3] = f2bf_rne(x[3]);
    u[4] = f2bf_rne(y[0]); u[5] = f2bf_rne(y[1]); u[6] = f2bf_rne(y[2]); u[7] = f2bf_rne(y[3]);
    return __builtin_bit_cast(bf16x8, u);
}

// ---------------- K1f: fused GEMM + hB-swizzle + e_src/e_dst ----------------
// 256 blocks x 256 thr. Block = 16 rows; wave hh owns cols [64hh,64hh+64) = head hh.
__global__ __launch_bounds__(256) void k1_fused(const float* __restrict__ X,
                                                const float* __restrict__ W,
                                                const float* __restrict__ bias,
                                                const float* __restrict__ a,
                                                unsigned short* __restrict__ hB,
                                                float* __restrict__ esrc,
                                                float* __restrict__ edst) {
    const int lane = threadIdx.x & 63;
    const int hh   = threadIdx.x >> 6;      // head / column group
    const int row  = lane & 15;
    const int kg   = lane >> 4;
    const int rowbase = blockIdx.x * 16;

    f32x4 acc[4];
#pragma unroll
    for (int n = 0; n < 4; ++n) acc[n] = (f32x4)0.f;

#pragma unroll
    for (int kk = 0; kk < 8; ++kk) {
        const int kb = kk * 32 + kg * 8;
        bf16x8 a0 = ld_cvt8(X + (rowbase + row) * 256 + kb);
#pragma unroll
        for (int n = 0; n < 4; ++n) {
            bf16x8 bb = ld_cvt8(W + (hh * 64 + n * 16 + row) * 256 + kb);
            acc[n] = __builtin_amdgcn_mfma_f32_16x16x32_bf16(a0, bb, acc[n], 0, 0, 0);
        }
    }

    const int t   = rowbase >> 5;
    const int lp  = (((rowbase >> 4) & 1) * 2 + (kg >> 1)) * 16 + row;
    const int eoff = (kg & 1) * 4;
    unsigned short* hbb = hB + (hh * 128 + t) * 2048 + lp * 8 + eoff;

    float eS0 = 0.f, eS1 = 0.f, eS2 = 0.f, eS3 = 0.f;
    float eT0 = 0.f, eT1 = 0.f, eT2 = 0.f, eT3 = 0.f;
#pragma unroll
    for (int n = 0; n < 4; ++n) {
        const int col = hh * 64 + n * 16 + row;
        const float bv = bias[col];
        f32x4 hv;
        hv[0] = acc[n][0] + bv; hv[1] = acc[n][1] + bv;
        hv[2] = acc[n][2] + bv; hv[3] = acc[n][3] + bv;
        u16x4 us;
        us[0] = f2bf_rne(hv[0]); us[1] = f2bf_rne(hv[1]);
        us[2] = f2bf_rne(hv[2]); us[3] = f2bf_rne(hv[3]);
        *(u16x4*)(hbb + n * 512) = us;
        const float as_ = a[hh * 128 + n * 16 + row];
        const float ad_ = a[hh * 128 + 64 + n * 16 + row];
        eS0 += hv[0] * as_; eS1 += hv[1] * as_; eS2 += hv[2] * as_; eS3 += hv[3] * as_;
        eT0 += hv[0] * ad_; eT1 += hv[1] * ad_; eT2 += hv[2] * ad_; eT3 += hv[3] * ad_;
    }
#pragma unroll
    for (int d = 1; d < 16; d <<= 1) {
        eS0 += __shfl_xor(eS0, d); eS1 += __shfl_xor(eS1, d);
        eS2 += __shfl_xor(eS2, d); eS3 += __shfl_xor(eS3, d);
        eT0 += __shfl_xor(eT0, d); eT1 += __shfl_xor(eT1, d);
        eT2 += __shfl_xor(eT2, d); eT3 += __shfl_xor(eT3, d);
    }
    if (row == 0) {
        const int rb = hh * NN + rowbase + kg * 4;
        esrc[rb + 0] = eS0 * LOG2E; esrc[rb + 1] = eS1 * LOG2E;
        esrc[rb + 2] = eS2 * LOG2E; esrc[rb + 3] = eS3 * LOG2E;
        edst[rb + 0] = eT0 * LOG2E; edst[rb + 1] = eT1 * LOG2E;
        edst[rb + 2] = eT2 * LOG2E; edst[rb + 3] = eT3 * LOG2E;
    }
}

// ---------------- K3: async-staged adj masked softmax (m=0) + P@H ----------------
// grid 256: hh = bx>>6, ib = bx&63 (XCD = bx%8 = ib%8 -> 4 heads of an ib
// share an XCD L2). Rows i0 = ib*64 .. +64. 8 waves: rg = w>>1 (16 rows),
// jh = w&1 (j-half of 2048). 32 iterations x 2 tiles of 32 j.
// adj LDS layout per wave: [16 rows][64 ints], int-index XOR-swizzled by
// (row&3)<<3 on BOTH the staged global source and the read (involution).
#define K3_MKP(AF, ES, M8) {                                                      \
    f32x4 s0v = E0 + (f32x4)(ES);                                                 \
    f32x4 s1v = E1 + (f32x4)(ES);                                                 \
    s0v = __builtin_elementwise_max(s0v, s0v * 0.2f);                             \
    s1v = __builtin_elementwise_max(s1v, s1v * 0.2f);                             \
    AF[0] = (__bf16)__builtin_exp2f(s0v[0]);                                      \
    AF[1] = (__bf16)__builtin_exp2f(s0v[1]);                                      \
    AF[2] = (__bf16)__builtin_exp2f(s0v[2]);                                      \
    AF[3] = (__bf16)__builtin_exp2f(s0v[3]);                                      \
    AF[4] = (__bf16)__builtin_exp2f(s1v[0]);                                      \
    AF[5] = (__bf16)__builtin_exp2f(s1v[1]);                                      \
    AF[6] = (__bf16)__builtin_exp2f(s1v[2]);                                      \
    AF[7] = (__bf16)__builtin_exp2f(s1v[3]);                                      \
    u32x4 aw = __builtin_bit_cast(u32x4, AF);                                     \
    const u32x2 mk0 = mlut[(M8) & 15u];                                           \
    const u32x2 mk1 = mlut[((M8) >> 4) & 15u];                                    \
    aw[0] &= mk0[0]; aw[1] &= mk0[1];                                             \
    aw[2] &= mk1[0]; aw[3] &= mk1[1];                                             \
    AF = __builtin_bit_cast(bf16x8, aw);                                          \
}

#define K3_STAGE(IT, BUF) {                                                       \
    _Pragma("unroll")                                                             \
    for (int k = 0; k < 4; ++k)                                                   \
        __builtin_amdgcn_global_load_lds(                                         \
            (const __attribute__((address_space(1))) void*)(gbase + (size_t)k * 16384 + (IT) * 64), \
            (__attribute__((address_space(3))) void*)(&abuf[w][BUF][4 * k][0]),   \
            16, 0, 0);                                                            \
}

#define K3_BODY(IT, BUF) {                                                        \
    const unsigned int* ab = &abuf[w][BUF][0][0];                                 \
    _Pragma("unroll")                                                             \
    for (int lt = 0; lt < 2; ++lt) {                                              \
        const int tl = (IT) * 2 + lt;                                             \
        const int iloc = (lt * 32 + kg8) ^ rsw;                                   \
        const u32x4 v0 = *(const u32x4*)(ab + row * 64 + iloc);                   \
        const u32x4 v1 = *(const u32x4*)(ab + row * 64 + iloc + 4);               \
        const f32x4 E0 = *(const f32x4*)(eD + tl * 32);                           \
        const f32x4 E1 = *(const f32x4*)(eD + tl * 32 + 4);                       \
        const u16x8 B0 = *(const u16x8*)(hBp + tl * 2048);                        \
        const u16x8 B1 = *(const u16x8*)(hBp + tl * 2048 + 512);                  \
        const u16x8 B2 = *(const u16x8*)(hBp + tl * 2048 + 1024);                 \
        const u16x8 B3 = *(const u16x8*)(hBp + tl * 2048 + 1536);                 \
        unsigned m8 = (v0[0] & 1u)        | ((v0[1] & 1u) << 1)                   \
                    | ((v0[2] & 1u) << 2) | ((v0[3] & 1u) << 3)                   \
                    | ((v1[0] & 1u) << 4) | ((v1[1] & 1u) << 5)                   \
                    | ((v1[2] & 1u) << 6) | ((v1[3] & 1u) << 7);                  \
        bf16x8 af;                                                                \
        K3_MKP(af, es0, m8)                                                       \
        a0 = __builtin_amdgcn_mfma_f32_16x16x32_bf16(af, __builtin_bit_cast(bf16x8, B0), a0, 0, 0, 0); \
        a1 = __builtin_amdgcn_mfma_f32_16x16x32_bf16(af, __builtin_bit_cast(bf16x8, B1), a1, 0, 0, 0); \
        a2 = __builtin_amdgcn_mfma_f32_16x16x32_bf16(af, __builtin_bit_cast(bf16x8, B2), a2, 0, 0, 0); \
        a3 = __builtin_amdgcn_mfma_f32_16x16x32_bf16(af, __builtin_bit_cast(bf16x8, B3), a3, 0, 0, 0); \
        a4 = __builtin_amdgcn_mfma_f32_16x16x32_bf16(af, bOnes, a4, 0, 0, 0);     \
    }                                                                             \
}

__global__ __launch_bounds__(512, 2) void k3_flash(const int* __restrict__ adj,
                                                   const unsigned short* __restrict__ hB,
                                                   const float* __restrict__ esrc,
                                                   const float* __restrict__ edst,
                                                   float* __restrict__ out) {
    __shared__ unsigned int abuf[8][3][16][64];   // 96 KB: per-wave 3-buf adj
    __shared__ float lacc[8][16][64];             // 32 KB
    __shared__ float lls[8][16];
    __shared__ u32x2 mlut[16];

    const int lane = threadIdx.x & 63;
    const int w  = threadIdx.x >> 6;   // 0..7
    const int rg = w >> 1;             // rowgroup 0..3
    const int jh = w & 1;              // j-half 0/1
    const int hh = blockIdx.x >> 6;    // head
    const int ib = blockIdx.x & 63;    // XCD = ib%8 for all 4 heads
    const int i0 = ib * 64;
    const int row = lane & 15;
    const int kg  = lane >> 4;
    const int kg8 = kg * 8;
    const int rsw = (row & 3) << 3;

    if (threadIdx.x < 16) {
        const unsigned n = threadIdx.x;
        u32x2 m;
        m[0] = ((n & 1u) ? 0xFFFFu : 0u) | ((n & 2u) ? 0xFFFF0000u : 0u);
        m[1] = ((n & 4u) ? 0xFFFFu : 0u) | ((n & 8u) ? 0xFFFF0000u : 0u);
        mlut[n] = m;
    }
    __syncthreads();

    // stage source: inst k covers LDS rows 4k..4k+3; lane l -> row 4k+(l>>4),
    // ints 4(l&15)..+4; source col pre-swizzled by ((l>>4)&3)<<3.
    const int lr4  = lane >> 4;                       // 0..3
    const int gloc = (4 * (lane & 15)) ^ (lr4 << 3);
    const unsigned int* gbase = (const unsigned int*)adj
        + (size_t)(i0 + rg * 16 + lr4) * NN + jh * 2048 + gloc;

    const float es0 = esrc[hh * NN + i0 + rg * 16 + row];
    const float* eD = edst + hh * NN + jh * 2048 + kg8;
    const unsigned short* hBp = hB + (size_t)((hh * 128 + jh * 64) * 256 + lane) * 8;

    u16x8 ou;
    const unsigned short ov = (row == 0) ? (unsigned short)0x3F80 : (unsigned short)0;
#pragma unroll
    for (int e = 0; e < 8; ++e) ou[e] = ov;
    const bf16x8 bOnes = __builtin_bit_cast(bf16x8, ou);

    f32x4 a0 = (f32x4)0.f, a1 = (f32x4)0.f, a2 = (f32x4)0.f,
          a3 = (f32x4)0.f, a4 = (f32x4)0.f;

    K3_STAGE(0, 0)
    K3_STAGE(1, 1)
    for (int it = 0; it < 31; ++it) {
        asm volatile("s_waitcnt vmcnt(4)" ::: "memory");
        __builtin_amdgcn_sched_barrier(0);
        const int bf = it % 3;
        K3_BODY(it, bf)
        if (it < 30) {
            const int sb = (it + 2) % 3;
            K3_STAGE(it + 2, sb)
        }
    }
    asm volatile("s_waitcnt vmcnt(0)" ::: "memory");
    __builtin_amdgcn_sched_barrier(0);
    K3_BODY(31, 1)   // 31 % 3 == 1

    // ---- dump wave partials ----
#pragma unroll
    for (int n = 0; n < 4; ++n) {
        f32x4 an = (n == 0) ? a0 : (n == 1) ? a1 : (n == 2) ? a2 : a3;
#pragma unroll
        for (int r = 0; r < 4; ++r)
            lacc[w][kg * 4 + r][n * 16 + row] = an[r];
    }
    if (row == 0) {
#pragma unroll
        for (int r = 0; r < 4; ++r) lls[w][kg * 4 + r] = a4[r];
    }
    __syncthreads();

    // ---- merge the 2 j-halves per rowgroup, normalize, write out ----
    {
        const int rg2 = threadIdx.x >> 7;         // 0..3
        const int r2  = (threadIdx.x >> 3) & 15;  // 0..15
        const int c8  = (threadIdx.x & 7) * 8;    // 0..56
        const int wA = rg2 * 2, wB = rg2 * 2 + 1;
        f32x4 v0 = *(const f32x4*)&lacc[wA][r2][c8];
        f32x4 v1 = *(const f32x4*)&lacc[wA][r2][c8 + 4];
        v0 += *(const f32x4*)&lacc[wB][r2][c8];
        v1 += *(const f32x4*)&lacc[wB][r2][c8 + 4];
        const float inv = 1.f / (lls[wA][r2] + lls[wB][r2]);
        f32x4 o0, o1;
        o0[0] = v0[0] * inv; o0[1] = v0[1] * inv; o0[2] = v0[2] * inv; o0[3] = v0[3] * inv;
        o1[0] = v1[0] * inv; o1[1] = v1[1] * inv; o1[2] = v1[2] * inv; o1[3] = v1[3] * inv;
        float* op = out + (size_t)(i0 + rg2 * 16 + r2) * 256 + hh * 64 + c8;
        *(f32x4*)op = o0;
        *(f32x4*)(op + 4) = o1;
    }
}

extern "C" void kernel_launch(void* const* d_in, const int* in_sizes, int n_in,
                              void* d_out, int out_size, void* d_ws, size_t ws_size,
                              hipStream_t stream) {
    const float* X    = (const float*)d_in[0];
    const int*   adj  = (const int*)d_in[1];
    const float* W    = (const float*)d_in[2];
    const float* bias = (const float*)d_in[3];
    const float* a    = (const float*)d_in[4];
    float* out = (float*)d_out;

    char* ws = (char*)d_ws;
    unsigned short* hB   = (unsigned short*)(ws);                         // 2 MB
    float*          esrc = (float*)(ws + (2 << 20));                      // 64 KB (HEADS*N)
    float*          edst = (float*)(ws + (2 << 20) + (64 << 10));         // 64 KB (HEADS*N)

    k1_fused<<<256, 256, 0, stream>>>(X, W, bias, a, hB, esrc, edst);
    k3_flash<<<256, 512, 0, stream>>>(adj, hB, esrc, edst, out);
}

// Round 13
// 56.027 us; speedup vs baseline: 1.2158x; 1.1842x over previous
//
#include <hip/hip_runtime.h>
#include <hip/hip_bf16.h>

// GAT layer, N=4096, C_IN=C_OUT=256, HEADS=4, C_HEAD=64.
// Pipeline (3 kernels):
//  K0: ballot-pack adj (64 MB int32 0/1) -> 2 MB bitmask, natural j-order:
//      mw32[m] bit b = adj[m*32+b]. One dense dword/lane/iter (256B per
//      wave-instruction), __ballot packs 64 lanes/instr, 8-deep unroll.
//  K1f: h = X@W^T + b in-register; writes hB (bf16 MFMA-B-fragment order)
//       + e_src/e_dst (x log2e). h fp32 never materialized.  [r10 verbatim]
//  K3: masked softmax (fixed m=0) + P@H from bitmask; packed f32 VALU math,
//      16-entry LDS LUT mask expansion, 32 i-rows/wave, 8 j-splits merged
//      via LDS. 33KB LDS -> 4 blocks/CU (8 waves/SIMD).  [r10 verbatim]
// Workspace: ~4.2 MB.

#define NN 4096
#define LOG2E 1.4426950408889634f

typedef float f32x4 __attribute__((ext_vector_type(4)));
typedef int i32x4 __attribute__((ext_vector_type(4)));
typedef unsigned int u32x2 __attribute__((ext_vector_type(2)));
typedef unsigned int u32x4 __attribute__((ext_vector_type(4)));
typedef unsigned short u16x4 __attribute__((ext_vector_type(4)));
typedef unsigned short u16x8 __attribute__((ext_vector_type(8)));
typedef __bf16 bf16x8 __attribute__((ext_vector_type(8)));

__device__ __forceinline__ unsigned short f2bf_rne(float f) {
    unsigned int u = __builtin_bit_cast(unsigned int, f);
    u += 0x7fffu + ((u >> 16) & 1u);
    return (unsigned short)(u >> 16);
}

__device__ __forceinline__ bf16x8 ld_cvt8(const float* __restrict__ p) {
    f32x4 x = *(const f32x4*)p;
    f32x4 y = *(const f32x4*)(p + 4);
    u16x8 u;
    u[0] = f2bf_rne(x[0]); u[1] = f2bf_rne(x[1]); u[2] = f2bf_rne(x[2]); u[3] = f2bf_rne(x[3]);
    u[4] = f2bf_rne(y[0]); u[5] = f2bf_rne(y[1]); u[6] = f2bf_rne(y[2]); u[7] = f2bf_rne(y[3]);
    return __builtin_bit_cast(bf16x8, u);
}

// ---------------- K0: ballot-pack adj -> natural-order bitmask ----------------
// Wave wg covers ints [wg*2048, wg*2048+2048). Iter (o,i): lane reads
// adj[wg*2048 + o*512 + i*64 + lane]; ballot -> u64 word (wg*32 + o*8 + i).
__global__ __launch_bounds__(256) void k0_pack(const int* __restrict__ adj,
                                               unsigned long long* __restrict__ mw64) {
    const int wg   = (blockIdx.x * 256 + threadIdx.x) >> 6;   // 0 .. 8191
    const int lane = threadIdx.x & 63;
    const int* base = adj + wg * 2048 + lane;
    unsigned long long* outb = mw64 + wg * 32;

#pragma unroll
    for (int o = 0; o < 4; ++o) {
        int v0 = base[o * 512 + 0 * 64];
        int v1 = base[o * 512 + 1 * 64];
        int v2 = base[o * 512 + 2 * 64];
        int v3 = base[o * 512 + 3 * 64];
        int v4 = base[o * 512 + 4 * 64];
        int v5 = base[o * 512 + 5 * 64];
        int v6 = base[o * 512 + 6 * 64];
        int v7 = base[o * 512 + 7 * 64];
        unsigned long long b0 = __ballot(v0 & 1);
        unsigned long long b1 = __ballot(v1 & 1);
        unsigned long long b2 = __ballot(v2 & 1);
        unsigned long long b3 = __ballot(v3 & 1);
        unsigned long long b4 = __ballot(v4 & 1);
        unsigned long long b5 = __ballot(v5 & 1);
        unsigned long long b6 = __ballot(v6 & 1);
        unsigned long long b7 = __ballot(v7 & 1);
        const int s = lane & 7;
        unsigned long long sel = b0;
        sel = (s == 1) ? b1 : sel;
        sel = (s == 2) ? b2 : sel;
        sel = (s == 3) ? b3 : sel;
        sel = (s == 4) ? b4 : sel;
        sel = (s == 5) ? b5 : sel;
        sel = (s == 6) ? b6 : sel;
        sel = (s == 7) ? b7 : sel;
        if (lane < 8) outb[o * 8 + lane] = sel;
    }
}

// ---------------- K1f: fused GEMM + hB-swizzle + e_src/e_dst ----------------
// 256 blocks x 256 thr. Block = 16 rows; wave hh owns cols [64hh,64hh+64) = head hh.
__global__ __launch_bounds__(256) void k1_fused(const float* __restrict__ X,
                                                const float* __restrict__ W,
                                                const float* __restrict__ bias,
                                                const float* __restrict__ a,
                                                unsigned short* __restrict__ hB,
                                                float* __restrict__ esrc,
                                                float* __restrict__ edst) {
    const int lane = threadIdx.x & 63;
    const int hh   = threadIdx.x >> 6;      // head / column group
    const int row  = lane & 15;
    const int kg   = lane >> 4;
    const int rowbase = blockIdx.x * 16;

    f32x4 acc[4];
#pragma unroll
    for (int n = 0; n < 4; ++n) acc[n] = (f32x4)0.f;

#pragma unroll
    for (int kk = 0; kk < 8; ++kk) {
        const int kb = kk * 32 + kg * 8;
        bf16x8 a0 = ld_cvt8(X + (rowbase + row) * 256 + kb);
#pragma unroll
        for (int n = 0; n < 4; ++n) {
            bf16x8 bb = ld_cvt8(W + (hh * 64 + n * 16 + row) * 256 + kb);
            acc[n] = __builtin_amdgcn_mfma_f32_16x16x32_bf16(a0, bb, acc[n], 0, 0, 0);
        }
    }

    // epilogue: bias, hB store (fragment order), e_src/e_dst dots
    // value acc[n][r] = h[rowbase+4kg+r][hh*64 + n*16 + row]
    // -> hB lane' = (rb2*2 + (kg>>1))*16 + row, e = (kg&1)*4 + r
    const int t   = rowbase >> 5;
    const int lp  = (((rowbase >> 4) & 1) * 2 + (kg >> 1)) * 16 + row;
    const int eoff = (kg & 1) * 4;
    unsigned short* hbb = hB + (hh * 128 + t) * 2048 + lp * 8 + eoff;

    float eS0 = 0.f, eS1 = 0.f, eS2 = 0.f, eS3 = 0.f;
    float eT0 = 0.f, eT1 = 0.f, eT2 = 0.f, eT3 = 0.f;
#pragma unroll
    for (int n = 0; n < 4; ++n) {
        const int col = hh * 64 + n * 16 + row;
        const float bv = bias[col];
        f32x4 hv;
        hv[0] = acc[n][0] + bv; hv[1] = acc[n][1] + bv;
        hv[2] = acc[n][2] + bv; hv[3] = acc[n][3] + bv;
        u16x4 us;
        us[0] = f2bf_rne(hv[0]); us[1] = f2bf_rne(hv[1]);
        us[2] = f2bf_rne(hv[2]); us[3] = f2bf_rne(hv[3]);
        *(u16x4*)(hbb + n * 512) = us;
        const float as_ = a[hh * 128 + n * 16 + row];
        const float ad_ = a[hh * 128 + 64 + n * 16 + row];
        eS0 += hv[0] * as_; eS1 += hv[1] * as_; eS2 += hv[2] * as_; eS3 += hv[3] * as_;
        eT0 += hv[0] * ad_; eT1 += hv[1] * ad_; eT2 += hv[2] * ad_; eT3 += hv[3] * ad_;
    }
#pragma unroll
    for (int d = 1; d < 16; d <<= 1) {
        eS0 += __shfl_xor(eS0, d); eS1 += __shfl_xor(eS1, d);
        eS2 += __shfl_xor(eS2, d); eS3 += __shfl_xor(eS3, d);
        eT0 += __shfl_xor(eT0, d); eT1 += __shfl_xor(eT1, d);
        eT2 += __shfl_xor(eT2, d); eT3 += __shfl_xor(eT3, d);
    }
    if (row == 0) {
        const int rb = hh * NN + rowbase + kg * 4;
        esrc[rb + 0] = eS0 * LOG2E; esrc[rb + 1] = eS1 * LOG2E;
        esrc[rb + 2] = eS2 * LOG2E; esrc[rb + 3] = eS3 * LOG2E;
        edst[rb + 0] = eT0 * LOG2E; edst[rb + 1] = eT1 * LOG2E;
        edst[rb + 2] = eT2 * LOG2E; edst[rb + 3] = eT3 * LOG2E;
    }
}

// ---------------- K3: bitmask softmax (m=0) + P@H ----------------
// grid 512: ib = bx>>2 (32 rows), hh = bx&3. 8 waves = 8 j-splits of 512 j.
// Each wave: 2 row-groups (i0+row, i0+16+row) x 16 tiles of 32 j.
// Mask word per tile (natural j order); lane (row,kg) uses bits kg*8..kg*8+7.
#define K3_MKP(AF, ES, MW) {                                                      \
    f32x4 s0v = E0 + (f32x4)(ES);                                                 \
    f32x4 s1v = E1 + (f32x4)(ES);                                                 \
    s0v = __builtin_elementwise_max(s0v, s0v * 0.2f);                             \
    s1v = __builtin_elementwise_max(s1v, s1v * 0.2f);                             \
    bf16x8 afv;                                                                   \
    afv[0] = (__bf16)__builtin_exp2f(s0v[0]);                                     \
    afv[1] = (__bf16)__builtin_exp2f(s0v[1]);                                     \
    afv[2] = (__bf16)__builtin_exp2f(s0v[2]);                                     \
    afv[3] = (__bf16)__builtin_exp2f(s0v[3]);                                     \
    afv[4] = (__bf16)__builtin_exp2f(s1v[0]);                                     \
    afv[5] = (__bf16)__builtin_exp2f(s1v[1]);                                     \
    afv[6] = (__bf16)__builtin_exp2f(s1v[2]);                                     \
    afv[7] = (__bf16)__builtin_exp2f(s1v[3]);                                     \
    u32x4 aw = __builtin_bit_cast(u32x4, afv);                                    \
    const u32x2 mk0 = mlut[((MW) >> kg8) & 15u];                                  \
    const u32x2 mk1 = mlut[(((MW) >> kg8) >> 4) & 15u];                           \
    aw[0] &= mk0[0]; aw[1] &= mk0[1];                                             \
    aw[2] &= mk1[0]; aw[3] &= mk1[1];                                             \
    AF = __builtin_bit_cast(bf16x8, aw);                                          \
}

__global__ __launch_bounds__(512, 4) void k3_flash(const unsigned int* __restrict__ mw32,
                                                   const unsigned short* __restrict__ hB,
                                                   const float* __restrict__ esrc,
                                                   const float* __restrict__ edst,
                                                   float* __restrict__ out) {
    __shared__ float lacc[8][16][64];
    __shared__ float lls[8][16];
    __shared__ u32x2 mlut[16];

    const int lane = threadIdx.x & 63;
    const int q  = threadIdx.x >> 6;  // j-split 0..7 (512 j each)
    const int hh = blockIdx.x & 3;    // head
    const int ib = blockIdx.x >> 2;   // 0..127
    const int i0 = ib * 32;
    const int row = lane & 15;
    const int kg  = lane >> 4;
    const int kg8 = kg * 8;

    if (threadIdx.x < 16) {
        const unsigned n = threadIdx.x;
        u32x2 m;
        m[0] = ((n & 1u) ? 0xFFFFu : 0u) | ((n & 2u) ? 0xFFFF0000u : 0u);
        m[1] = ((n & 4u) ? 0xFFFFu : 0u) | ((n & 8u) ? 0xFFFF0000u : 0u);
        mlut[n] = m;
    }
    __syncthreads();

    const float es0 = esrc[hh * NN + i0 + row];
    const float es1 = esrc[hh * NN + i0 + 16 + row];
    // tile words: mw32[i*128 + q*16 + tt], tt = td*4 + ti
    const unsigned int* mwp = mw32 + (i0 + row) * 128 + q * 16;
    const float* eD = edst + hh * NN + q * 512 + kg * 8;
    const unsigned short* hBp = hB + ((hh * 128 + q * 16) * 256 + lane) * 8;

    // ones B-fragment: column 0 only
    u16x8 ou;
    const unsigned short ov = (row == 0) ? (unsigned short)0x3F80 : (unsigned short)0;
#pragma unroll
    for (int e = 0; e < 8; ++e) ou[e] = ov;
    const bf16x8 bOnes = __builtin_bit_cast(bf16x8, ou);

    f32x4 aA0 = (f32x4)0.f, aA1 = (f32x4)0.f, aA2 = (f32x4)0.f,
          aA3 = (f32x4)0.f, aA4 = (f32x4)0.f;
    f32x4 aB0 = (f32x4)0.f, aB1 = (f32x4)0.f, aB2 = (f32x4)0.f,
          aB3 = (f32x4)0.f, aB4 = (f32x4)0.f;

    for (int td = 0; td < 4; ++td) {
        const u32x4 M0 = *(const u32x4*)(mwp + td * 4);
        const u32x4 M1 = *(const u32x4*)(mwp + 16 * 128 + td * 4);
        const float* eDt = eD + td * 128;
        const unsigned short* hBt = hBp + td * 8192;
#pragma unroll
        for (int ti = 0; ti < 4; ++ti) {
            const f32x4 E0 = *(const f32x4*)(eDt + ti * 32);
            const f32x4 E1 = *(const f32x4*)(eDt + ti * 32 + 4);
            const u16x8 B0 = *(const u16x8*)(hBt + ti * 2048);
            const u16x8 B1 = *(const u16x8*)(hBt + ti * 2048 + 512);
            const u16x8 B2 = *(const u16x8*)(hBt + ti * 2048 + 1024);
            const u16x8 B3 = *(const u16x8*)(hBt + ti * 2048 + 1536);
            bf16x8 af0, af1;
            K3_MKP(af0, es0, M0[ti])
            K3_MKP(af1, es1, M1[ti])
            aA0 = __builtin_amdgcn_mfma_f32_16x16x32_bf16(af0, __builtin_bit_cast(bf16x8, B0), aA0, 0, 0, 0);
            aA1 = __builtin_amdgcn_mfma_f32_16x16x32_bf16(af0, __builtin_bit_cast(bf16x8, B1), aA1, 0, 0, 0);
            aA2 = __builtin_amdgcn_mfma_f32_16x16x32_bf16(af0, __builtin_bit_cast(bf16x8, B2), aA2, 0, 0, 0);
            aA3 = __builtin_amdgcn_mfma_f32_16x16x32_bf16(af0, __builtin_bit_cast(bf16x8, B3), aA3, 0, 0, 0);
            aA4 = __builtin_amdgcn_mfma_f32_16x16x32_bf16(af0, bOnes, aA4, 0, 0, 0);
            aB0 = __builtin_amdgcn_mfma_f32_16x16x32_bf16(af1, __builtin_bit_cast(bf16x8, B0), aB0, 0, 0, 0);
            aB1 = __builtin_amdgcn_mfma_f32_16x16x32_bf16(af1, __builtin_bit_cast(bf16x8, B1), aB1, 0, 0, 0);
            aB2 = __builtin_amdgcn_mfma_f32_16x16x32_bf16(af1, __builtin_bit_cast(bf16x8, B2), aB2, 0, 0, 0);
            aB3 = __builtin_amdgcn_mfma_f32_16x16x32_bf16(af1, __builtin_bit_cast(bf16x8, B3), aB3, 0, 0, 0);
            aB4 = __builtin_amdgcn_mfma_f32_16x16x32_bf16(af1, bOnes, aB4, 0, 0, 0);
        }
    }

    // ---- merge pass 1: row-group 0 (rows i0 .. i0+15) ----
#pragma unroll
    for (int n = 0; n < 4; ++n) {
        f32x4 an = (n == 0) ? aA0 : (n == 1) ? aA1 : (n == 2) ? aA2 : aA3;
#pragma unroll
        for (int r = 0; r < 4; ++r)
            lacc[q][kg * 4 + r][n * 16 + row] = an[r];
    }
    if (row == 0) {
#pragma unroll
        for (int r = 0; r < 4; ++r) lls[q][kg * 4 + r] = aA4[r];
    }
    __syncthreads();
    if (threadIdx.x < 256) {
        const int idx = threadIdx.x * 4;
        const int r2 = idx >> 6;
        const int c  = idx & 63;
        f32x4 v = (f32x4)0.f;
        float l = 0.f;
#pragma unroll
        for (int q2 = 0; q2 < 8; ++q2) {
            v += *(const f32x4*)&lacc[q2][r2][c];
            l += lls[q2][r2];
        }
        const float inv = 1.f / l;
        f32x4 o;
        o[0] = v[0] * inv; o[1] = v[1] * inv; o[2] = v[2] * inv; o[3] = v[3] * inv;
        *(f32x4*)(out + (i0 + r2) * 256 + hh * 64 + c) = o;
    }
    __syncthreads();

    // ---- merge pass 2: row-group 1 (rows i0+16 .. i0+31) ----
#pragma unroll
    for (int n = 0; n < 4; ++n) {
        f32x4 an = (n == 0) ? aB0 : (n == 1) ? aB1 : (n == 2) ? aB2 : aB3;
#pragma unroll
        for (int r = 0; r < 4; ++r)
            lacc[q][kg * 4 + r][n * 16 + row] = an[r];
    }
    if (row == 0) {
#pragma unroll
        for (int r = 0; r < 4; ++r) lls[q][kg * 4 + r] = aB4[r];
    }
    __syncthreads();
    if (threadIdx.x < 256) {
        const int idx = threadIdx.x * 4;
        const int r2 = idx >> 6;
        const int c  = idx & 63;
        f32x4 v = (f32x4)0.f;
        float l = 0.f;
#pragma unroll
        for (int q2 = 0; q2 < 8; ++q2) {
            v += *(const f32x4*)&lacc[q2][r2][c];
            l += lls[q2][r2];
        }
        const float inv = 1.f / l;
        f32x4 o;
        o[0] = v[0] * inv; o[1] = v[1] * inv; o[2] = v[2] * inv; o[3] = v[3] * inv;
        *(f32x4*)(out + (i0 + 16 + r2) * 256 + hh * 64 + c) = o;
    }
}

extern "C" void kernel_launch(void* const* d_in, const int* in_sizes, int n_in,
                              void* d_out, int out_size, void* d_ws, size_t ws_size,
                              hipStream_t stream) {
    const float* X    = (const float*)d_in[0];
    const int*   adj  = (const int*)d_in[1];
    const float* W    = (const float*)d_in[2];
    const float* bias = (const float*)d_in[3];
    const float* a    = (const float*)d_in[4];
    float* out = (float*)d_out;

    char* ws = (char*)d_ws;
    unsigned int*   mw   = (unsigned int*)(ws);                           // 2 MB
    unsigned short* hB   = (unsigned short*)(ws + (2 << 20));             // 2 MB
    float*          esrc = (float*)(ws + (4 << 20));                      // 64 KB (HEADS*N)
    float*          edst = (float*)(ws + (4 << 20) + (64 << 10));         // 64 KB (HEADS*N)

    k0_pack<<<2048, 256, 0, stream>>>(adj, (unsigned long long*)mw);
    k1_fused<<<256, 256, 0, stream>>>(X, W, bias, a, hB, esrc, edst);
    k3_flash<<<512, 512, 0, stream>>>(mw, hB, esrc, edst, out);
}